// Round 21
// baseline (163.777 us; speedup 1.0000x reference)
//
#include <hip/hip_runtime.h>
#include <math.h>

#define BB    32
#define TENC  1024
#define TDEC  512
#define DDIM  512
#define NST   512

typedef _Float16 f16_t;
typedef _Float16 f16x8 __attribute__((ext_vector_type(8)));
typedef _Float16 f16x4 __attribute__((ext_vector_type(4)));
typedef float    f32x4 __attribute__((ext_vector_type(4)));

#define GLOAD_LDS16(gp, lp) __builtin_amdgcn_global_load_lds( \
    (const __attribute__((address_space(1))) unsigned int*)(const void*)(gp), \
    (__attribute__((address_space(3))) unsigned int*)(lp), 16, 0, 0)

static __device__ __forceinline__ f32x4 MFMA16H(f16x8 a, f16x8 b, f32x4 c) {
    return __builtin_amdgcn_mfma_f32_16x16x32_f16(a, b, c, 0, 0, 0);
}

// ---------------------------------------------------------------------------
// Fused prep: enc->f16 (blocks 0..8191); Wk->f16 REPLICATED x32 (8192..8319);
// Wv->f16 transposed REPLICATED x32 (8320..8383).
// Replication spreads the weight across addresses so the ~1000 GEMM blocks
// don't all hammer the same 0.5MB (suspected L2/L3 channel serialization).
__global__ __launch_bounds__(256)
void prep_convert(const float* __restrict__ enc, const float* __restrict__ Wk,
                  const float* __restrict__ Wv,
                  f16_t* __restrict__ Ef16, f16_t* __restrict__ Wk16r,
                  f16_t* __restrict__ WvT16r)
{
    const int bid = blockIdx.x;
    const int t = threadIdx.x;
    const long nW = (long)DDIM * NST;   // 262144 elems per copy

    if (bid < 8192) {
        long i = (long)bid * 256 + t;
        float4 a = *(const float4*)&enc[i * 8];
        float4 b = *(const float4*)&enc[i * 8 + 4];
        f16x8 o;
        o[0] = (f16_t)a.x; o[1] = (f16_t)a.y; o[2] = (f16_t)a.z; o[3] = (f16_t)a.w;
        o[4] = (f16_t)b.x; o[5] = (f16_t)b.y; o[6] = (f16_t)b.z; o[7] = (f16_t)b.w;
        *(f16x8*)&Ef16[i * 8] = o;
        return;
    }

    if (bid < 8320) {
        long i = (long)(bid - 8192) * 256 + t;
        float4 a = *(const float4*)&Wk[i * 8];
        float4 b = *(const float4*)&Wk[i * 8 + 4];
        f16x8 o;
        o[0] = (f16_t)a.x; o[1] = (f16_t)a.y; o[2] = (f16_t)a.z; o[3] = (f16_t)a.w;
        o[4] = (f16_t)b.x; o[5] = (f16_t)b.y; o[6] = (f16_t)b.z; o[7] = (f16_t)b.w;
#pragma unroll
        for (int rcp = 0; rcp < BB; ++rcp)
            *(f16x8*)&Wk16r[rcp * nW + i * 8] = o;
        return;
    }

    // WvT[v][d] = Wv[d][v], replicated x32
    __shared__ f16_t tile[64][65];
    const int r2 = bid - 8320;
    const int c0 = (r2 & 7) * 64, r0 = (r2 >> 3) * 64;
    const int rr = t >> 4;
    const int cc = (t & 15) * 4;
#pragma unroll
    for (int p = 0; p < 4; ++p) {
        int r = rr + p * 16;
        float4 v = *(const float4*)&Wv[(long)(r0 + r) * NST + c0 + cc];
        tile[r][cc + 0] = (f16_t)v.x;
        tile[r][cc + 1] = (f16_t)v.y;
        tile[r][cc + 2] = (f16_t)v.z;
        tile[r][cc + 3] = (f16_t)v.w;
    }
    __syncthreads();
    const int dr = t >> 2;
    const int tc = (t & 3) * 16;
    f16_t tmp[16];
#pragma unroll
    for (int e = 0; e < 16; ++e) tmp[e] = tile[tc + e][dr];
    const long off = (long)(c0 + dr) * DDIM + r0 + tc;
#pragma unroll
    for (int rcp = 0; rcp < BB; ++rcp) {
        *(f16x8*)&WvT16r[rcp * nW + off]     = *(f16x8*)&tmp[0];
        *(f16x8*)&WvT16r[rcp * nW + off + 8] = *(f16x8*)&tmp[8];
    }
}

// ---------------------------------------------------------------------------
// Reg-staged GEMM (R15/R20-proven): C = opA[M,K] @ opB[N,K]^T (+bias).
// AREG=1: A is f32 reg-staged (Rf), B = f16 gload (Gh). EPI: 2=f16 out.
template<int AREG, int EPI>
__global__ __launch_bounds__(256)
void gemm_rs(const float* __restrict__ Rf, const f16_t* __restrict__ Gh,
             const float* __restrict__ bias, void* __restrict__ C0,
             int M, int N, int K, long sRf, long sG, long sC)
{
    __shared__ f16_t lds[2][8192];   // A-half [0,4096), B-half [4096,8192)

    const int tid  = threadIdx.x;
    const int wave = tid >> 6;
    const int lane = tid & 63;

    const int gx = gridDim.x, gy = gridDim.y;
    const long nwg = (long)gx * gy * gridDim.z;
    const long fo  = ((long)blockIdx.z * gy + blockIdx.y) * gx + blockIdx.x;
    const long f2 = (fo & 7) * (nwg >> 3) + (fo >> 3);
    const int bx  = (int)(f2 % gx);
    const int by  = (int)((f2 / gx) % gy);
    const long bz = f2 / ((long)gx * gy);

    const float* RfB = Rf + bz * sRf;
    const f16_t* GhB = Gh + bz * sG;

    const int row0 = by * 128;
    const int col0 = bx * 128;
    const int rbase = AREG ? row0 : col0;
    const int gbase = AREG ? col0 : row0;
    constexpr int rOff = AREG ? 0 : 4096;
    constexpr int gOff = AREG ? 4096 : 0;

    const int srow  = wave * 16 + (lane >> 2);
    const int sslot = (lane & 3) ^ ((srow >> 1) & 3);
    const int wdst  = wave * 512;

    const int rrow = tid >> 3;
    const int rk4  = (tid & 7) * 4;
    const int rgr  = rk4 >> 3;
    const int rh4  = rk4 & 4;

    const int fr = lane & 15;
    const int q  = lane >> 4;
    const int wr = (wave >> 1) * 64;
    const int wc = (wave & 1) * 64;
    int aro[4], bro[4];
#pragma unroll
    for (int i = 0; i < 4; ++i) {
        const int r = wr + i * 16 + fr;
        aro[i] = r * 32 + ((q ^ ((r >> 1) & 3)) * 8);
    }
#pragma unroll
    for (int j = 0; j < 4; ++j) {
        const int r = wc + j * 16 + fr;
        bro[j] = r * 32 + ((q ^ ((r >> 1) & 3)) * 8);
    }

    f32x4 acc[4][4] = {};
    float4 rS[4];
    f16x8 aH[4], bH[4];
    const int NT = K >> 5;

    auto stageG = [&](f16_t* buf, int kt) {
#pragma unroll
        for (int c = 0; c < 2; ++c) {
            const long go = (long)(gbase + c * 64 + srow) * K + kt + sslot * 8;
            GLOAD_LDS16(GhB + go, &buf[gOff + c * 2048 + wdst]);
        }
    };
    auto loadR = [&](int kt) {
#pragma unroll
        for (int i = 0; i < 4; ++i)
            rS[i] = *(const float4*)&RfB[(long)(rbase + i * 32 + rrow) * K + kt + rk4];
    };
    auto writeR = [&](f16_t* buf) {
#pragma unroll
        for (int i = 0; i < 4; ++i) {
            const int row = i * 32 + rrow;
            const int eo  = row * 32 + ((rgr ^ ((row >> 1) & 3)) * 8) + rh4;
            f16x4 h4;
            h4[0] = (f16_t)rS[i].x; h4[1] = (f16_t)rS[i].y;
            h4[2] = (f16_t)rS[i].z; h4[3] = (f16_t)rS[i].w;
            *(f16x4*)&buf[rOff + eo] = h4;
        }
    };
    auto readF = [&](const f16_t* buf) {
#pragma unroll
        for (int i = 0; i < 4; ++i) aH[i] = *(const f16x8*)&buf[aro[i]];
#pragma unroll
        for (int j = 0; j < 4; ++j) bH[j] = *(const f16x8*)&buf[4096 + bro[j]];
    };

    loadR(0);
    stageG(lds[0], 0);
    writeR(lds[0]);
    loadR(32);
    asm volatile("s_waitcnt vmcnt(4)" ::: "memory");
    asm volatile("s_waitcnt lgkmcnt(0)" ::: "memory");
    __builtin_amdgcn_s_barrier();
    readF(lds[0]);
    asm volatile("s_waitcnt lgkmcnt(0)" ::: "memory");
    __builtin_amdgcn_s_barrier();

    for (int t = 0; t < NT; ++t) {
        f16_t* nxt = lds[(t & 1) ^ 1];
        const bool pf = (t + 1 < NT);

        if (pf) {
            writeR(nxt);
            stageG(nxt, (t + 1) << 5);
            if (t + 2 < NT) loadR((t + 2) << 5);
        }
#pragma unroll
        for (int j = 0; j < 4; ++j)
#pragma unroll
            for (int i = 0; i < 4; ++i)
                acc[i][j] = MFMA16H(aH[i], bH[j], acc[i][j]);

        if (pf && (t + 2 < NT))
            asm volatile("s_waitcnt vmcnt(4)" ::: "memory");
        else
            asm volatile("s_waitcnt vmcnt(0)" ::: "memory");
        asm volatile("s_waitcnt lgkmcnt(0)" ::: "memory");
        __builtin_amdgcn_s_barrier();
        if (pf) {
            readF(nxt);
            asm volatile("s_waitcnt lgkmcnt(0)" ::: "memory");
        }
        __builtin_amdgcn_s_barrier();
    }

    const int frow = q * 4;
#pragma unroll
    for (int i = 0; i < 4; ++i) {
        const int rgl = row0 + wr + i * 16 + frow;
#pragma unroll
        for (int j = 0; j < 4; ++j) {
            const int cg = col0 + wc + j * 16 + fr;
            if constexpr (EPI == 2) {
                f16_t* C = (f16_t*)C0 + bz * sC;
#pragma unroll
                for (int r = 0; r < 4; ++r)
                    C[(long)(rgl + r) * N + cg] = (f16_t)acc[i][j][r];
            } else if constexpr (EPI == 0) {
                float* C = (float*)C0 + bz * sC;
#pragma unroll
                for (int r = 0; r < 4; ++r)
                    C[(long)(rgl + r) * N + cg] = acc[i][j][r];
            } else {
                float* C = (float*)C0 + bz * sC;
                const float badd = bias[cg];
#pragma unroll
                for (int r = 0; r < 4; ++r)
                    C[(long)(rgl + r) * N + cg] = acc[i][j][r] + badd;
            }
        }
    }
}

// ---------------------------------------------------------------------------
// Plain-f16 MFMA GEMM, both operands gload (R10/R20-proven): C = A @ B'^T (+bias).
// EPI: 0 = f32, 2 = f16, 3 = f32+bias.
template<int EPI>
__global__ __launch_bounds__(256)
void gemm_h(const f16_t* __restrict__ A, const f16_t* __restrict__ B,
            const float* __restrict__ bias, void* __restrict__ C0,
            int M, int N, int K, long sA, long sB, long sC)
{
    __shared__ f16_t lds[2][8192];

    const int tid  = threadIdx.x;
    const int wave = tid >> 6;
    const int lane = tid & 63;

    const int gx = gridDim.x, gy = gridDim.y;
    const long nwg = (long)gx * gy * gridDim.z;
    const long fo  = ((long)blockIdx.z * gy + blockIdx.y) * gx + blockIdx.x;
    const long f2 = (fo & 7) * (nwg >> 3) + (fo >> 3);
    const int bx  = (int)(f2 % gx);
    const int by  = (int)((f2 / gx) % gy);
    const long bz = f2 / ((long)gx * gy);

    const f16_t* Ab = A + bz * sA;
    const f16_t* Bb = B + bz * sB;

    const int row0 = by * 128;
    const int col0 = bx * 128;

    const int srow  = wave * 16 + (lane >> 2);
    const int sslot = (lane & 3) ^ ((srow >> 1) & 3);
    const int wdst  = wave * 512;
    const long aOff0 = (long)(row0 + srow) * K + sslot * 8;
    const long aOff1 = (long)(row0 + 64 + srow) * K + sslot * 8;
    const long bOff0 = (long)(col0 + srow) * K + sslot * 8;
    const long bOff1 = (long)(col0 + 64 + srow) * K + sslot * 8;

    const int fr = lane & 15;
    const int q  = lane >> 4;
    const int wr = (wave >> 1) * 64;
    const int wc = (wave & 1) * 64;
    int aro[4], bro[4];
#pragma unroll
    for (int i = 0; i < 4; ++i) {
        const int r = wr + i * 16 + fr;
        aro[i] = r * 32 + ((q ^ ((r >> 1) & 3)) * 8);
    }
#pragma unroll
    for (int j = 0; j < 4; ++j) {
        const int r = wc + j * 16 + fr;
        bro[j] = r * 32 + ((q ^ ((r >> 1) & 3)) * 8);
    }

    f32x4 acc[4][4] = {};
    const int NT = K >> 5;

#define STAGE(buf, kt) do {                                   \
        GLOAD_LDS16(Ab + aOff0 + (kt), &(buf)[wdst]);         \
        GLOAD_LDS16(Ab + aOff1 + (kt), &(buf)[2048 + wdst]);  \
        GLOAD_LDS16(Bb + bOff0 + (kt), &(buf)[4096 + wdst]);  \
        GLOAD_LDS16(Bb + bOff1 + (kt), &(buf)[6144 + wdst]);  \
    } while (0)

    STAGE(lds[0], 0);

    for (int t = 0; t < NT; ++t) {
        const f16_t* cur = lds[t & 1];
        f16_t* nxt = lds[(t & 1) ^ 1];
        const bool pf = (t + 1 < NT);

        __builtin_amdgcn_sched_barrier(0);
        __builtin_amdgcn_s_barrier();
        if (pf) {
            STAGE(nxt, (t + 1) << 5);
            asm volatile("s_waitcnt vmcnt(4)" ::: "memory");
        } else {
            asm volatile("s_waitcnt vmcnt(0)" ::: "memory");
        }
        __builtin_amdgcn_s_barrier();
        __builtin_amdgcn_sched_barrier(0);

        f16x8 aH[4], bH[4];
#pragma unroll
        for (int i = 0; i < 4; ++i) aH[i] = *(const f16x8*)&cur[aro[i]];
#pragma unroll
        for (int j = 0; j < 4; ++j) bH[j] = *(const f16x8*)&cur[4096 + bro[j]];

#pragma unroll
        for (int j = 0; j < 4; ++j)
#pragma unroll
            for (int i = 0; i < 4; ++i)
                acc[i][j] = MFMA16H(aH[i], bH[j], acc[i][j]);
    }
#undef STAGE

    const int frow = q * 4;
#pragma unroll
    for (int i = 0; i < 4; ++i) {
        const int rgl = row0 + wr + i * 16 + frow;
#pragma unroll
        for (int j = 0; j < 4; ++j) {
            const int cg = col0 + wc + j * 16 + fr;
            if constexpr (EPI == 2) {
                f16_t* C = (f16_t*)C0 + bz * sC;
#pragma unroll
                for (int r = 0; r < 4; ++r)
                    C[(long)(rgl + r) * N + cg] = (f16_t)acc[i][j][r];
            } else if constexpr (EPI == 0) {
                float* C = (float*)C0 + bz * sC;
#pragma unroll
                for (int r = 0; r < 4; ++r)
                    C[(long)(rgl + r) * N + cg] = acc[i][j][r];
            } else {
                float* C = (float*)C0 + bz * sC;
                const float badd = bias[cg];
#pragma unroll
                for (int r = 0; r < 4; ++r)
                    C[(long)(rgl + r) * N + cg] = acc[i][j][r] + badd;
            }
        }
    }
}

// ---------------------------------------------------------------------------
// Row softmax over length-1024 rows, f32 in place + f16 copy (R10-proven).
__global__ __launch_bounds__(256)
void softmax_rows(float* __restrict__ S, f16_t* __restrict__ Sh)
{
    const long row = (long)blockIdx.x * 4 + (threadIdx.x >> 6);
    const int lane = threadIdx.x & 63;
    float* p = S + row * (long)TENC;

    float4 v[4];
    float m = -INFINITY;
#pragma unroll
    for (int i = 0; i < 4; ++i) {
        v[i] = *(const float4*)&p[i * 256 + lane * 4];
        m = fmaxf(fmaxf(fmaxf(v[i].x, v[i].y), fmaxf(v[i].z, v[i].w)), m);
    }
#pragma unroll
    for (int o = 32; o; o >>= 1) m = fmaxf(m, __shfl_xor(m, o, 64));

    float s = 0.f;
#pragma unroll
    for (int i = 0; i < 4; ++i) {
        v[i].x = __expf(v[i].x - m);
        v[i].y = __expf(v[i].y - m);
        v[i].z = __expf(v[i].z - m);
        v[i].w = __expf(v[i].w - m);
        s += v[i].x + v[i].y + v[i].z + v[i].w;
    }
#pragma unroll
    for (int o = 32; o; o >>= 1) s += __shfl_xor(s, o, 64);

    const float inv = 1.0f / s;
#pragma unroll
    for (int i = 0; i < 4; ++i) {
        v[i].x *= inv; v[i].y *= inv; v[i].z *= inv; v[i].w *= inv;
        *(float4*)&p[i * 256 + lane * 4] = v[i];
        if (Sh) {
            f16x4 h;
            h[0] = (f16_t)v[i].x; h[1] = (f16_t)v[i].y;
            h[2] = (f16_t)v[i].z; h[3] = (f16_t)v[i].w;
            *(f16x4*)&Sh[row * (long)TENC + i * 256 + lane * 4] = h;
        }
    }
}

// ---------------------------------------------------------------------------
// fp32 fallback GEMM (safety net for tiny ws)
#define TILE_M 64
#define TILE_N 64
#define TILE_K 16
template<bool B_TRANS, bool ADD_BIAS>
__global__ __launch_bounds__(256)
void gemm_f32(const float* __restrict__ A, const float* __restrict__ Bm,
              const float* __restrict__ bias, float* __restrict__ C,
              int M, int N, int K, int lda, int ldb,
              long strideA, long strideB, long strideC)
{
    __shared__ float As[TILE_K][TILE_M + 4];
    __shared__ float Bs[TILE_K][TILE_N + 4];
    const int b = blockIdx.z;
    A += (long)b * strideA; Bm += (long)b * strideB; C += (long)b * strideC;
    const int tid = threadIdx.x;
    const int tx = tid & 15, ty = tid >> 4;
    const int row0 = blockIdx.y * TILE_M, col0 = blockIdx.x * TILE_N;
    const int am = tid >> 2, ak = (tid & 3) * 4;
    float acc[4][4] = {};
    for (int kt = 0; kt < K; kt += TILE_K) {
        float4 a4 = *(const float4*)&A[(long)(row0 + am) * lda + kt + ak];
        float4 b4;
        if (B_TRANS) b4 = *(const float4*)&Bm[(long)(col0 + am) * ldb + kt + ak];
        else {
            const int bk_ = tid >> 4, bn = (tid & 15) * 4;
            b4 = *(const float4*)&Bm[(long)(kt + bk_) * ldb + col0 + bn];
        }
        __syncthreads();
        As[ak + 0][am] = a4.x; As[ak + 1][am] = a4.y;
        As[ak + 2][am] = a4.z; As[ak + 3][am] = a4.w;
        if (B_TRANS) {
            Bs[ak + 0][am] = b4.x; Bs[ak + 1][am] = b4.y;
            Bs[ak + 2][am] = b4.z; Bs[ak + 3][am] = b4.w;
        } else {
            const int bk_ = tid >> 4, bn = (tid & 15) * 4;
            *(float4*)&Bs[bk_][bn] = b4;
        }
        __syncthreads();
#pragma unroll
        for (int k = 0; k < TILE_K; ++k) {
            float4 av = *(const float4*)&As[k][ty * 4];
            float4 bv4 = *(const float4*)&Bs[k][tx * 4];
            float ar[4] = {av.x, av.y, av.z, av.w};
            float br[4] = {bv4.x, bv4.y, bv4.z, bv4.w};
#pragma unroll
            for (int i = 0; i < 4; ++i)
#pragma unroll
                for (int j = 0; j < 4; ++j)
                    acc[i][j] = fmaf(ar[i], br[j], acc[i][j]);
        }
    }
    float4 bias4 = make_float4(0.f, 0.f, 0.f, 0.f);
    if (ADD_BIAS) bias4 = *(const float4*)&bias[col0 + tx * 4];
#pragma unroll
    for (int i = 0; i < 4; ++i) {
        float4 o;
        o.x = acc[i][0] + bias4.x; o.y = acc[i][1] + bias4.y;
        o.z = acc[i][2] + bias4.z; o.w = acc[i][3] + bias4.w;
        *(float4*)&C[(long)(row0 + ty * 4 + i) * N + col0 + tx * 4] = o;
    }
}

// ---------------------------------------------------------------------------
extern "C" void kernel_launch(void* const* d_in, const int* in_sizes, int n_in,
                              void* d_out, int out_size, void* d_ws, size_t ws_size,
                              hipStream_t stream)
{
    const float* enc = (const float*)d_in[0];   // [32,1024,512]
    const float* dec = (const float*)d_in[1];   // [32,512,512]
    const float* Wk  = (const float*)d_in[2];   // [512,512]
    const float* Wv  = (const float*)d_in[4];   // [512,512]
    const float* bv  = (const float*)d_in[5];   // [512]

    const long nD = (long)BB * TDEC * NST;      // 8388608
    const long nW = (long)DDIM * NST;           // 262144

    float* ctx   = (float*)d_out;               // [32,512,512]
    float* attnF = ctx + nD;                    // [32,512,1024]

    const size_t need = 67108864;
    const dim3 blk(256);

    if (ws_size < need) {
        float* ws = (float*)d_ws;
        gemm_f32<true, false><<<dim3(DDIM / 64, (BB * TDEC) / 64, 1), blk, 0, stream>>>(
            dec, Wk, nullptr, ws, BB * TDEC, DDIM, NST, NST, NST, 0, 0, 0);
        gemm_f32<true, false><<<dim3(TENC / 64, TDEC / 64, BB), blk, 0, stream>>>(
            ws, enc, nullptr, attnF, TDEC, TENC, DDIM, DDIM, DDIM,
            (long)TDEC * DDIM, (long)TENC * DDIM, (long)TDEC * TENC);
        softmax_rows<<<(BB * TDEC) / 4, blk, 0, stream>>>(attnF, nullptr);
        gemm_f32<false, false><<<dim3(DDIM / 64, TDEC / 64, BB), blk, 0, stream>>>(
            attnF, enc, nullptr, ws, TDEC, DDIM, TENC, TENC, DDIM,
            (long)TDEC * TENC, (long)TENC * DDIM, (long)TDEC * DDIM);
        gemm_f32<false, true><<<dim3(NST / 64, (BB * TDEC) / 64, 1), blk, 0, stream>>>(
            ws, Wv, bv, ctx, BB * TDEC, NST, DDIM, DDIM, NST, 0, 0, 0);
        return;
    }

    // ws: EVT 33.55MB | Ef16 33.55MB
    char* w = (char*)d_ws;
    f16_t* EVT  = (f16_t*)(w);
    f16_t* Ef16 = (f16_t*)(w + 33554432);
    f16_t* attnB = Ef16;   // alias: live only after score+EVT consumed Ef16

    // d_out scratch: ctx region = DK16 (16.78MB) + Wk16r (16.78MB, 32 copies);
    // attn region head = WvT16r (16.78MB, 32 copies; dead once EVT is done,
    // then overwritten by score's attn write).
    f16_t* DK16   = (f16_t*)ctx;
    f16_t* Wk16r  = DK16 + nD;
    f16_t* WvT16r = (f16_t*)attnF;

    // 1) fused prep: enc->f16; Wk,WvT -> f16 replicated x32
    prep_convert<<<8384, blk, 0, stream>>>(enc, Wk, Wv, Ef16, Wk16r, WvT16r);

    // 2) DK[z][q,d] = sum_n dec[z][q,n] Wk[d,n]  (batched; per-batch Wk copy)
    gemm_rs<1, 2><<<dim3(DDIM / 128, TDEC / 128, BB), blk, 0, stream>>>(
        dec, Wk16r, nullptr, DK16,
        TDEC, DDIM, NST,
        (long)TDEC * NST, nW, (long)TDEC * DDIM);

    // 3) EVT[z][v,te] = sum_d WvT[v,d] enc16[z][te,d]  (per-batch WvT copy)
    //    MUST run before score overwrites the attn region (WvT16r lives there).
    gemm_h<2><<<dim3(TENC / 128, NST / 128, BB), blk, 0, stream>>>(
        WvT16r, Ef16, nullptr, EVT,
        NST, TENC, DDIM,
        nW, (long)TENC * DDIM, (long)NST * TENC);

    // 4) score[q,te] = sum_d DK[q,d] enc16[te,d] -> f32 attn region
    gemm_h<0><<<dim3(TENC / 128, TDEC / 128, BB), blk, 0, stream>>>(
        DK16, Ef16, nullptr, attnF,
        TDEC, TENC, DDIM,
        (long)TDEC * DDIM, (long)TENC * DDIM, (long)TDEC * TENC);

    // 5) softmax f32 in place + f16 copy over the dead Ef16 region
    softmax_rows<<<(BB * TDEC) / 4, blk, 0, stream>>>(attnF, attnB);

    // 6) ctx = attn @ EV + bv  (attnB f16 gload, EVT gload) -> f32+bias
    gemm_h<3><<<dim3(NST / 128, TDEC / 128, BB), blk, 0, stream>>>(
        attnB, EVT, bv, ctx,
        TDEC, NST, TENC,
        (long)TDEC * TENC, (long)NST * TENC, (long)TDEC * NST);
}

// Round 22
// 162.634 us; speedup vs baseline: 1.0070x; 1.0070x over previous
//
#include <hip/hip_runtime.h>
#include <math.h>

#define BB    32
#define TENC  1024
#define TDEC  512
#define DDIM  512
#define NST   512

typedef _Float16 f16_t;
typedef _Float16 f16x8 __attribute__((ext_vector_type(8)));
typedef _Float16 f16x4 __attribute__((ext_vector_type(4)));
typedef float    f32x4 __attribute__((ext_vector_type(4)));

#define GLOAD_LDS16(gp, lp) __builtin_amdgcn_global_load_lds( \
    (const __attribute__((address_space(1))) unsigned int*)(const void*)(gp), \
    (__attribute__((address_space(3))) unsigned int*)(lp), 16, 0, 0)

static __device__ __forceinline__ f32x4 MFMA16H(f16x8 a, f16x8 b, f32x4 c) {
    return __builtin_amdgcn_mfma_f32_16x16x32_f16(a, b, c, 0, 0, 0);
}

// ---------------------------------------------------------------------------
// Fused prep (R20-proven): enc->f16 (0..8191), Wk->f16 (8192..8319),
// Wv->f16 transposed (8320..8383).
__global__ __launch_bounds__(256)
void prep_convert(const float* __restrict__ enc, const float* __restrict__ Wk,
                  const float* __restrict__ Wv,
                  f16_t* __restrict__ Ef16, f16_t* __restrict__ Wk16,
                  f16_t* __restrict__ WvT16)
{
    const int bid = blockIdx.x;
    const int t = threadIdx.x;

    if (bid < 8320) {
        const float* src; f16_t* dst; long i;
        if (bid < 8192) { src = enc; dst = Ef16; i = (long)bid * 256 + t; }
        else            { src = Wk;  dst = Wk16; i = (long)(bid - 8192) * 256 + t; }
        float4 a = *(const float4*)&src[i * 8];
        float4 b = *(const float4*)&src[i * 8 + 4];
        f16x8 o;
        o[0] = (f16_t)a.x; o[1] = (f16_t)a.y; o[2] = (f16_t)a.z; o[3] = (f16_t)a.w;
        o[4] = (f16_t)b.x; o[5] = (f16_t)b.y; o[6] = (f16_t)b.z; o[7] = (f16_t)b.w;
        *(f16x8*)&dst[i * 8] = o;
        return;
    }

    __shared__ f16_t tile[64][65];
    const int r2 = bid - 8320;
    const int c0 = (r2 & 7) * 64, r0 = (r2 >> 3) * 64;
    const int rr = t >> 4;
    const int cc = (t & 15) * 4;
#pragma unroll
    for (int p = 0; p < 4; ++p) {
        int r = rr + p * 16;
        float4 v = *(const float4*)&Wv[(long)(r0 + r) * NST + c0 + cc];
        tile[r][cc + 0] = (f16_t)v.x;
        tile[r][cc + 1] = (f16_t)v.y;
        tile[r][cc + 2] = (f16_t)v.z;
        tile[r][cc + 3] = (f16_t)v.w;
    }
    __syncthreads();
    const int dr = t >> 2;
    const int tc = (t & 3) * 16;
    f16_t tmp[16];
#pragma unroll
    for (int e = 0; e < 16; ++e) tmp[e] = tile[tc + e][dr];
    *(f16x8*)&WvT16[(long)(c0 + dr) * DDIM + r0 + tc]     = *(f16x8*)&tmp[0];
    *(f16x8*)&WvT16[(long)(c0 + dr) * DDIM + r0 + tc + 8] = *(f16x8*)&tmp[8];
}

// ---------------------------------------------------------------------------
// Reg-staged GEMM (R20-proven): C = opA[M,K] @ opB[N,K]^T.
// AREG=1: A is f32 reg-staged (Rf), B = f16 gload (Gh). EPI: 2=f16 out.
template<int AREG, int EPI>
__global__ __launch_bounds__(256)
void gemm_rs(const float* __restrict__ Rf, const f16_t* __restrict__ Gh,
             const float* __restrict__ bias, void* __restrict__ C0,
             int M, int N, int K, long sRf, long sG, long sC)
{
    __shared__ f16_t lds[2][8192];

    const int tid  = threadIdx.x;
    const int wave = tid >> 6;
    const int lane = tid & 63;

    const int gx = gridDim.x, gy = gridDim.y;
    const long nwg = (long)gx * gy * gridDim.z;
    const long fo  = ((long)blockIdx.z * gy + blockIdx.y) * gx + blockIdx.x;
    const long f2 = (fo & 7) * (nwg >> 3) + (fo >> 3);
    const int bx  = (int)(f2 % gx);
    const int by  = (int)((f2 / gx) % gy);
    const long bz = f2 / ((long)gx * gy);

    const float* RfB = Rf + bz * sRf;
    const f16_t* GhB = Gh + bz * sG;

    const int row0 = by * 128;
    const int col0 = bx * 128;
    const int rbase = AREG ? row0 : col0;
    const int gbase = AREG ? col0 : row0;
    constexpr int rOff = AREG ? 0 : 4096;
    constexpr int gOff = AREG ? 4096 : 0;

    const int srow  = wave * 16 + (lane >> 2);
    const int sslot = (lane & 3) ^ ((srow >> 1) & 3);
    const int wdst  = wave * 512;

    const int rrow = tid >> 3;
    const int rk4  = (tid & 7) * 4;
    const int rgr  = rk4 >> 3;
    const int rh4  = rk4 & 4;

    const int fr = lane & 15;
    const int q  = lane >> 4;
    const int wr = (wave >> 1) * 64;
    const int wc = (wave & 1) * 64;
    int aro[4], bro[4];
#pragma unroll
    for (int i = 0; i < 4; ++i) {
        const int r = wr + i * 16 + fr;
        aro[i] = r * 32 + ((q ^ ((r >> 1) & 3)) * 8);
    }
#pragma unroll
    for (int j = 0; j < 4; ++j) {
        const int r = wc + j * 16 + fr;
        bro[j] = r * 32 + ((q ^ ((r >> 1) & 3)) * 8);
    }

    f32x4 acc[4][4] = {};
    float4 rS[4];
    f16x8 aH[4], bH[4];
    const int NT = K >> 5;

    auto stageG = [&](f16_t* buf, int kt) {
#pragma unroll
        for (int c = 0; c < 2; ++c) {
            const long go = (long)(gbase + c * 64 + srow) * K + kt + sslot * 8;
            GLOAD_LDS16(GhB + go, &buf[gOff + c * 2048 + wdst]);
        }
    };
    auto loadR = [&](int kt) {
#pragma unroll
        for (int i = 0; i < 4; ++i)
            rS[i] = *(const float4*)&RfB[(long)(rbase + i * 32 + rrow) * K + kt + rk4];
    };
    auto writeR = [&](f16_t* buf) {
#pragma unroll
        for (int i = 0; i < 4; ++i) {
            const int row = i * 32 + rrow;
            const int eo  = row * 32 + ((rgr ^ ((row >> 1) & 3)) * 8) + rh4;
            f16x4 h4;
            h4[0] = (f16_t)rS[i].x; h4[1] = (f16_t)rS[i].y;
            h4[2] = (f16_t)rS[i].z; h4[3] = (f16_t)rS[i].w;
            *(f16x4*)&buf[rOff + eo] = h4;
        }
    };
    auto readF = [&](const f16_t* buf) {
#pragma unroll
        for (int i = 0; i < 4; ++i) aH[i] = *(const f16x8*)&buf[aro[i]];
#pragma unroll
        for (int j = 0; j < 4; ++j) bH[j] = *(const f16x8*)&buf[4096 + bro[j]];
    };

    loadR(0);
    stageG(lds[0], 0);
    writeR(lds[0]);
    loadR(32);
    asm volatile("s_waitcnt vmcnt(4)" ::: "memory");
    asm volatile("s_waitcnt lgkmcnt(0)" ::: "memory");
    __builtin_amdgcn_s_barrier();
    readF(lds[0]);
    asm volatile("s_waitcnt lgkmcnt(0)" ::: "memory");
    __builtin_amdgcn_s_barrier();

    for (int t = 0; t < NT; ++t) {
        f16_t* nxt = lds[(t & 1) ^ 1];
        const bool pf = (t + 1 < NT);

        if (pf) {
            writeR(nxt);
            stageG(nxt, (t + 1) << 5);
            if (t + 2 < NT) loadR((t + 2) << 5);
        }
#pragma unroll
        for (int j = 0; j < 4; ++j)
#pragma unroll
            for (int i = 0; i < 4; ++i)
                acc[i][j] = MFMA16H(aH[i], bH[j], acc[i][j]);

        if (pf && (t + 2 < NT))
            asm volatile("s_waitcnt vmcnt(4)" ::: "memory");
        else
            asm volatile("s_waitcnt vmcnt(0)" ::: "memory");
        asm volatile("s_waitcnt lgkmcnt(0)" ::: "memory");
        __builtin_amdgcn_s_barrier();
        if (pf) {
            readF(nxt);
            asm volatile("s_waitcnt lgkmcnt(0)" ::: "memory");
        }
        __builtin_amdgcn_s_barrier();
    }

    const int frow = q * 4;
#pragma unroll
    for (int i = 0; i < 4; ++i) {
        const int rgl = row0 + wr + i * 16 + frow;
#pragma unroll
        for (int j = 0; j < 4; ++j) {
            const int cg = col0 + wc + j * 16 + fr;
            if constexpr (EPI == 2) {
                f16_t* C = (f16_t*)C0 + bz * sC;
#pragma unroll
                for (int r = 0; r < 4; ++r)
                    C[(long)(rgl + r) * N + cg] = (f16_t)acc[i][j][r];
            } else if constexpr (EPI == 0) {
                float* C = (float*)C0 + bz * sC;
#pragma unroll
                for (int r = 0; r < 4; ++r)
                    C[(long)(rgl + r) * N + cg] = acc[i][j][r];
            } else {
                float* C = (float*)C0 + bz * sC;
                const float badd = bias[cg];
#pragma unroll
                for (int r = 0; r < 4; ++r)
                    C[(long)(rgl + r) * N + cg] = acc[i][j][r] + badd;
            }
        }
    }
}

// ---------------------------------------------------------------------------
// Plain-f16 MFMA GEMM, both gload (R20-proven): C = A @ B'^T (+bias).
// EPI: 0 = f32, 2 = f16, 3 = f32+bias.
template<int EPI>
__global__ __launch_bounds__(256)
void gemm_h(const f16_t* __restrict__ A, const f16_t* __restrict__ B,
            const float* __restrict__ bias, void* __restrict__ C0,
            int M, int N, int K, long sA, long sB, long sC)
{
    __shared__ f16_t lds[2][8192];

    const int tid  = threadIdx.x;
    const int wave = tid >> 6;
    const int lane = tid & 63;

    const int gx = gridDim.x, gy = gridDim.y;
    const long nwg = (long)gx * gy * gridDim.z;
    const long fo  = ((long)blockIdx.z * gy + blockIdx.y) * gx + blockIdx.x;
    const long f2 = (fo & 7) * (nwg >> 3) + (fo >> 3);
    const int bx  = (int)(f2 % gx);
    const int by  = (int)((f2 / gx) % gy);
    const long bz = f2 / ((long)gx * gy);

    const f16_t* Ab = A + bz * sA;
    const f16_t* Bb = B + bz * sB;

    const int row0 = by * 128;
    const int col0 = bx * 128;

    const int srow  = wave * 16 + (lane >> 2);
    const int sslot = (lane & 3) ^ ((srow >> 1) & 3);
    const int wdst  = wave * 512;
    const long aOff0 = (long)(row0 + srow) * K + sslot * 8;
    const long aOff1 = (long)(row0 + 64 + srow) * K + sslot * 8;
    const long bOff0 = (long)(col0 + srow) * K + sslot * 8;
    const long bOff1 = (long)(col0 + 64 + srow) * K + sslot * 8;

    const int fr = lane & 15;
    const int q  = lane >> 4;
    const int wr = (wave >> 1) * 64;
    const int wc = (wave & 1) * 64;
    int aro[4], bro[4];
#pragma unroll
    for (int i = 0; i < 4; ++i) {
        const int r = wr + i * 16 + fr;
        aro[i] = r * 32 + ((q ^ ((r >> 1) & 3)) * 8);
    }
#pragma unroll
    for (int j = 0; j < 4; ++j) {
        const int r = wc + j * 16 + fr;
        bro[j] = r * 32 + ((q ^ ((r >> 1) & 3)) * 8);
    }

    f32x4 acc[4][4] = {};
    const int NT = K >> 5;

#define STAGE(buf, kt) do {                                   \
        GLOAD_LDS16(Ab + aOff0 + (kt), &(buf)[wdst]);         \
        GLOAD_LDS16(Ab + aOff1 + (kt), &(buf)[2048 + wdst]);  \
        GLOAD_LDS16(Bb + bOff0 + (kt), &(buf)[4096 + wdst]);  \
        GLOAD_LDS16(Bb + bOff1 + (kt), &(buf)[6144 + wdst]);  \
    } while (0)

    STAGE(lds[0], 0);

    for (int t = 0; t < NT; ++t) {
        const f16_t* cur = lds[t & 1];
        f16_t* nxt = lds[(t & 1) ^ 1];
        const bool pf = (t + 1 < NT);

        __builtin_amdgcn_sched_barrier(0);
        __builtin_amdgcn_s_barrier();
        if (pf) {
            STAGE(nxt, (t + 1) << 5);
            asm volatile("s_waitcnt vmcnt(4)" ::: "memory");
        } else {
            asm volatile("s_waitcnt vmcnt(0)" ::: "memory");
        }
        __builtin_amdgcn_s_barrier();
        __builtin_amdgcn_sched_barrier(0);

        f16x8 aH[4], bH[4];
#pragma unroll
        for (int i = 0; i < 4; ++i) aH[i] = *(const f16x8*)&cur[aro[i]];
#pragma unroll
        for (int j = 0; j < 4; ++j) bH[j] = *(const f16x8*)&cur[4096 + bro[j]];

#pragma unroll
        for (int j = 0; j < 4; ++j)
#pragma unroll
            for (int i = 0; i < 4; ++i)
                acc[i][j] = MFMA16H(aH[i], bH[j], acc[i][j]);
    }
#undef STAGE

    const int frow = q * 4;
#pragma unroll
    for (int i = 0; i < 4; ++i) {
        const int rgl = row0 + wr + i * 16 + frow;
#pragma unroll
        for (int j = 0; j < 4; ++j) {
            const int cg = col0 + wc + j * 16 + fr;
            if constexpr (EPI == 2) {
                f16_t* C = (f16_t*)C0 + bz * sC;
#pragma unroll
                for (int r = 0; r < 4; ++r)
                    C[(long)(rgl + r) * N + cg] = (f16_t)acc[i][j][r];
            } else if constexpr (EPI == 0) {
                float* C = (float*)C0 + bz * sC;
#pragma unroll
                for (int r = 0; r < 4; ++r)
                    C[(long)(rgl + r) * N + cg] = acc[i][j][r];
            } else {
                float* C = (float*)C0 + bz * sC;
                const float badd = bias[cg];
#pragma unroll
                for (int r = 0; r < 4; ++r)
                    C[(long)(rgl + r) * N + cg] = acc[i][j][r] + badd;
            }
        }
    }
}

// ---------------------------------------------------------------------------
// Row softmax, f32 in place + f16 copy (R20-proven).
__global__ __launch_bounds__(256)
void softmax_rows(float* __restrict__ S, f16_t* __restrict__ Sh)
{
    const long row = (long)blockIdx.x * 4 + (threadIdx.x >> 6);
    const int lane = threadIdx.x & 63;
    float* p = S + row * (long)TENC;

    float4 v[4];
    float m = -INFINITY;
#pragma unroll
    for (int i = 0; i < 4; ++i) {
        v[i] = *(const float4*)&p[i * 256 + lane * 4];
        m = fmaxf(fmaxf(fmaxf(v[i].x, v[i].y), fmaxf(v[i].z, v[i].w)), m);
    }
#pragma unroll
    for (int o = 32; o; o >>= 1) m = fmaxf(m, __shfl_xor(m, o, 64));

    float s = 0.f;
#pragma unroll
    for (int i = 0; i < 4; ++i) {
        v[i].x = __expf(v[i].x - m);
        v[i].y = __expf(v[i].y - m);
        v[i].z = __expf(v[i].z - m);
        v[i].w = __expf(v[i].w - m);
        s += v[i].x + v[i].y + v[i].z + v[i].w;
    }
#pragma unroll
    for (int o = 32; o; o >>= 1) s += __shfl_xor(s, o, 64);

    const float inv = 1.0f / s;
#pragma unroll
    for (int i = 0; i < 4; ++i) {
        v[i].x *= inv; v[i].y *= inv; v[i].z *= inv; v[i].w *= inv;
        *(float4*)&p[i * 256 + lane * 4] = v[i];
        if (Sh) {
            f16x4 h;
            h[0] = (f16_t)v[i].x; h[1] = (f16_t)v[i].y;
            h[2] = (f16_t)v[i].z; h[3] = (f16_t)v[i].w;
            *(f16x4*)&Sh[row * (long)TENC + i * 256 + lane * 4] = h;
        }
    }
}

// ---------------------------------------------------------------------------
// fp32 fallback GEMM (safety net for tiny ws)
#define TILE_M 64
#define TILE_N 64
#define TILE_K 16
template<bool B_TRANS, bool ADD_BIAS>
__global__ __launch_bounds__(256)
void gemm_f32(const float* __restrict__ A, const float* __restrict__ Bm,
              const float* __restrict__ bias, float* __restrict__ C,
              int M, int N, int K, int lda, int ldb,
              long strideA, long strideB, long strideC)
{
    __shared__ float As[TILE_K][TILE_M + 4];
    __shared__ float Bs[TILE_K][TILE_N + 4];
    const int b = blockIdx.z;
    A += (long)b * strideA; Bm += (long)b * strideB; C += (long)b * strideC;
    const int tid = threadIdx.x;
    const int tx = tid & 15, ty = tid >> 4;
    const int row0 = blockIdx.y * TILE_M, col0 = blockIdx.x * TILE_N;
    const int am = tid >> 2, ak = (tid & 3) * 4;
    float acc[4][4] = {};
    for (int kt = 0; kt < K; kt += TILE_K) {
        float4 a4 = *(const float4*)&A[(long)(row0 + am) * lda + kt + ak];
        float4 b4;
        if (B_TRANS) b4 = *(const float4*)&Bm[(long)(col0 + am) * ldb + kt + ak];
        else {
            const int bk_ = tid >> 4, bn = (tid & 15) * 4;
            b4 = *(const float4*)&Bm[(long)(kt + bk_) * ldb + col0 + bn];
        }
        __syncthreads();
        As[ak + 0][am] = a4.x; As[ak + 1][am] = a4.y;
        As[ak + 2][am] = a4.z; As[ak + 3][am] = a4.w;
        if (B_TRANS) {
            Bs[ak + 0][am] = b4.x; Bs[ak + 1][am] = b4.y;
            Bs[ak + 2][am] = b4.z; Bs[ak + 3][am] = b4.w;
        } else {
            const int bk_ = tid >> 4, bn = (tid & 15) * 4;
            *(float4*)&Bs[bk_][bn] = b4;
        }
        __syncthreads();
#pragma unroll
        for (int k = 0; k < TILE_K; ++k) {
            float4 av = *(const float4*)&As[k][ty * 4];
            float4 bv4 = *(const float4*)&Bs[k][tx * 4];
            float ar[4] = {av.x, av.y, av.z, av.w};
            float br[4] = {bv4.x, bv4.y, bv4.z, bv4.w};
#pragma unroll
            for (int i = 0; i < 4; ++i)
#pragma unroll
                for (int j = 0; j < 4; ++j)
                    acc[i][j] = fmaf(ar[i], br[j], acc[i][j]);
        }
    }
    float4 bias4 = make_float4(0.f, 0.f, 0.f, 0.f);
    if (ADD_BIAS) bias4 = *(const float4*)&bias[col0 + tx * 4];
#pragma unroll
    for (int i = 0; i < 4; ++i) {
        float4 o;
        o.x = acc[i][0] + bias4.x; o.y = acc[i][1] + bias4.y;
        o.z = acc[i][2] + bias4.z; o.w = acc[i][3] + bias4.w;
        *(float4*)&C[(long)(row0 + ty * 4 + i) * N + col0 + tx * 4] = o;
    }
}

// ---------------------------------------------------------------------------
extern "C" void kernel_launch(void* const* d_in, const int* in_sizes, int n_in,
                              void* d_out, int out_size, void* d_ws, size_t ws_size,
                              hipStream_t stream)
{
    const float* enc = (const float*)d_in[0];   // [32,1024,512]
    const float* dec = (const float*)d_in[1];   // [32,512,512]
    const float* Wk  = (const float*)d_in[2];   // [512,512]
    const float* Wv  = (const float*)d_in[4];   // [512,512]
    const float* bv  = (const float*)d_in[5];   // [512]

    const long nD = (long)BB * TDEC * NST;      // 8388608

    float* ctx   = (float*)d_out;               // [32,512,512]
    float* attnF = ctx + nD;                    // [32,512,1024]

    const size_t need = 51380224;
    const dim3 blk(256);

    if (ws_size < need) {
        float* ws = (float*)d_ws;
        gemm_f32<true, false><<<dim3(DDIM / 64, (BB * TDEC) / 64, 1), blk, 0, stream>>>(
            dec, Wk, nullptr, ws, BB * TDEC, DDIM, NST, NST, NST, 0, 0, 0);
        gemm_f32<true, false><<<dim3(TENC / 64, TDEC / 64, BB), blk, 0, stream>>>(
            ws, enc, nullptr, attnF, TDEC, TENC, DDIM, DDIM, DDIM,
            (long)TDEC * DDIM, (long)TENC * DDIM, (long)TDEC * TENC);
        softmax_rows<<<(BB * TDEC) / 4, blk, 0, stream>>>(attnF, nullptr);
        gemm_f32<false, false><<<dim3(DDIM / 64, TDEC / 64, BB), blk, 0, stream>>>(
            attnF, enc, nullptr, ws, TDEC, DDIM, TENC, TENC, DDIM,
            (long)TDEC * TENC, (long)TENC * DDIM, (long)TDEC * DDIM);
        gemm_f32<false, true><<<dim3(NST / 64, (BB * TDEC) / 64, 1), blk, 0, stream>>>(
            ws, Wv, bv, ctx, BB * TDEC, NST, DDIM, DDIM, NST, 0, 0, 0);
        return;
    }

    // ws layout: Ef16 33.55MB @0 | EVT_B 16.78MB @33554432 | Wk16 @50331648 |
    //            WvT16 @50855936.  need = 51380224.
    char* w = (char*)d_ws;
    f16_t* Ef16  = (f16_t*)(w);
    f16_t* EVT_B = (f16_t*)(w + 33554432);       // batches 16..31 (ws control)
    f16_t* Wk16  = (f16_t*)(w + 50331648);
    f16_t* WvT16 = (f16_t*)(w + 50855936);
    f16_t* attnB = Ef16;   // alias: live only after score+EVT consumed Ef16

    // d_out ctx region (33.55MB): DK16 first half | EVT_A second half
    f16_t* DK16  = (f16_t*)ctx;                  // 16.78MB, dead after score
    f16_t* EVT_A = DK16 + nD;                    // batches 0..15 (d_out test)

    // 1) fused prep: enc->f16, Wk->f16, Wv->f16^T
    prep_convert<<<8384, blk, 0, stream>>>(enc, Wk, Wv, Ef16, Wk16, WvT16);

    // 2) DK[q,d] = sum_n dec[q,n] Wk[d,n]  (dec f32 reg-staged) -> f16
    gemm_rs<1, 2><<<dim3(DDIM / 128, (BB * TDEC) / 128, 1), blk, 0, stream>>>(
        dec, Wk16, nullptr, DK16,
        BB * TDEC, DDIM, NST, 0, 0, 0);

    // 3a) EVT-A: batches 0..15 -> d_out (ctx-region 2nd half)   [A/B test arm]
    gemm_h<2><<<dim3(TENC / 128, NST / 128, 16), blk, 0, stream>>>(
        WvT16, Ef16, nullptr, EVT_A,
        NST, TENC, DDIM,
        0, (long)TENC * DDIM, (long)NST * TENC);

    // 3b) EVT-B: batches 16..31 -> d_ws                          [control arm]
    gemm_h<2><<<dim3(TENC / 128, NST / 128, 16), blk, 0, stream>>>(
        WvT16, Ef16 + 16L * TENC * DDIM, nullptr, EVT_B,
        NST, TENC, DDIM,
        0, (long)TENC * DDIM, (long)NST * TENC);

    // 4) score[q,te] = sum_d DK[q,d] enc16[te,d] -> f32 attn region
    gemm_h<0><<<dim3(TENC / 128, TDEC / 128, BB), blk, 0, stream>>>(
        DK16, Ef16, nullptr, attnF,
        TDEC, TENC, DDIM,
        (long)TDEC * DDIM, (long)TENC * DDIM, (long)TDEC * TENC);

    // 5) softmax f32 in place + f16 copy over the dead Ef16 region
    softmax_rows<<<(BB * TDEC) / 4, blk, 0, stream>>>(attnF, attnB);

    // 6a) ctx L1: batches 0..15 (EVT from d_out; writes ctx 1st half — DK dead)
    gemm_h<3><<<dim3(NST / 128, TDEC / 128, 16), blk, 0, stream>>>(
        attnB, EVT_A, bv, ctx,
        TDEC, NST, TENC,
        (long)TDEC * TENC, (long)NST * TENC, (long)TDEC * NST);

    // 6b) ctx L2: batches 16..31 (EVT from ws; writes ctx 2nd half — EVT_A dead
    //     after L1 by stream order)
    gemm_h<3><<<dim3(NST / 128, TDEC / 128, 16), blk, 0, stream>>>(
        attnB + 16L * TDEC * TENC, EVT_B, bv, ctx + 16L * TDEC * NST,
        TDEC, NST, TENC,
        (long)TDEC * TENC, (long)NST * TENC, (long)TDEC * NST);
}

// Round 23
// 151.262 us; speedup vs baseline: 1.0827x; 1.0752x over previous
//
#include <hip/hip_runtime.h>
#include <math.h>

#define BB    32
#define TENC  1024
#define TDEC  512
#define DDIM  512
#define NST   512

typedef _Float16 f16_t;
typedef _Float16 f16x8 __attribute__((ext_vector_type(8)));
typedef _Float16 f16x4 __attribute__((ext_vector_type(4)));
typedef float    f32x4 __attribute__((ext_vector_type(4)));

#define GLOAD_LDS16(gp, lp) __builtin_amdgcn_global_load_lds( \
    (const __attribute__((address_space(1))) unsigned int*)(const void*)(gp), \
    (__attribute__((address_space(3))) unsigned int*)(lp), 16, 0, 0)

static __device__ __forceinline__ f32x4 MFMA16H(f16x8 a, f16x8 b, f32x4 c) {
    return __builtin_amdgcn_mfma_f32_16x16x32_f16(a, b, c, 0, 0, 0);
}

// ---------------------------------------------------------------------------
// Fused prep: enc->f16 (blocks 0..8191), Wk->f16 (8192..8319),
// Wv->f16 transposed (8320..8383). dec handled by reg-staged DK GEMM.
__global__ __launch_bounds__(256)
void prep_convert(const float* __restrict__ enc, const float* __restrict__ Wk,
                  const float* __restrict__ Wv,
                  f16_t* __restrict__ Ef16, f16_t* __restrict__ Wk16,
                  f16_t* __restrict__ WvT16)
{
    const int bid = blockIdx.x;
    const int t = threadIdx.x;

    if (bid < 8320) {
        const float* src; f16_t* dst; long i;
        if (bid < 8192) { src = enc; dst = Ef16; i = (long)bid * 256 + t; }
        else            { src = Wk;  dst = Wk16; i = (long)(bid - 8192) * 256 + t; }
        float4 a = *(const float4*)&src[i * 8];
        float4 b = *(const float4*)&src[i * 8 + 4];
        f16x8 o;
        o[0] = (f16_t)a.x; o[1] = (f16_t)a.y; o[2] = (f16_t)a.z; o[3] = (f16_t)a.w;
        o[4] = (f16_t)b.x; o[5] = (f16_t)b.y; o[6] = (f16_t)b.z; o[7] = (f16_t)b.w;
        *(f16x8*)&dst[i * 8] = o;
        return;
    }

    // WvT16[v][d] = Wv[d][v]
    __shared__ f16_t tile[64][65];
    const int r2 = bid - 8320;
    const int c0 = (r2 & 7) * 64, r0 = (r2 >> 3) * 64;
    const int rr = t >> 4;
    const int cc = (t & 15) * 4;
#pragma unroll
    for (int p = 0; p < 4; ++p) {
        int r = rr + p * 16;
        float4 v = *(const float4*)&Wv[(long)(r0 + r) * NST + c0 + cc];
        tile[r][cc + 0] = (f16_t)v.x;
        tile[r][cc + 1] = (f16_t)v.y;
        tile[r][cc + 2] = (f16_t)v.z;
        tile[r][cc + 3] = (f16_t)v.w;
    }
    __syncthreads();
    const int dr = t >> 2;
    const int tc = (t & 3) * 16;
    f16_t tmp[16];
#pragma unroll
    for (int e = 0; e < 16; ++e) tmp[e] = tile[tc + e][dr];
    *(f16x8*)&WvT16[(long)(c0 + dr) * DDIM + r0 + tc]     = *(f16x8*)&tmp[0];
    *(f16x8*)&WvT16[(long)(c0 + dr) * DDIM + r0 + tc + 8] = *(f16x8*)&tmp[8];
}

// ---------------------------------------------------------------------------
// Reg-staged GEMM: C = opA[M,K] @ opB[N,K]^T (+bias).
// AREG=1: A is f32 reg-staged (Rf), B = f16 gload (Gh). EPI: 2=f16 out.
template<int AREG, int EPI>
__global__ __launch_bounds__(256)
void gemm_rs(const float* __restrict__ Rf, const f16_t* __restrict__ Gh,
             const float* __restrict__ bias, void* __restrict__ C0,
             int M, int N, int K, long sRf, long sG, long sC)
{
    __shared__ f16_t lds[2][8192];   // A-half [0,4096), B-half [4096,8192)

    const int tid  = threadIdx.x;
    const int wave = tid >> 6;
    const int lane = tid & 63;

    const int gx = gridDim.x, gy = gridDim.y;
    const long nwg = (long)gx * gy * gridDim.z;
    const long fo  = ((long)blockIdx.z * gy + blockIdx.y) * gx + blockIdx.x;
    const long f2 = (fo & 7) * (nwg >> 3) + (fo >> 3);
    const int bx  = (int)(f2 % gx);
    const int by  = (int)((f2 / gx) % gy);
    const long bz = f2 / ((long)gx * gy);

    const float* RfB = Rf + bz * sRf;
    const f16_t* GhB = Gh + bz * sG;

    const int row0 = by * 128;
    const int col0 = bx * 128;
    const int rbase = AREG ? row0 : col0;
    const int gbase = AREG ? col0 : row0;
    constexpr int rOff = AREG ? 0 : 4096;
    constexpr int gOff = AREG ? 4096 : 0;

    const int srow  = wave * 16 + (lane >> 2);
    const int sslot = (lane & 3) ^ ((srow >> 1) & 3);
    const int wdst  = wave * 512;

    const int rrow = tid >> 3;
    const int rk4  = (tid & 7) * 4;
    const int rgr  = rk4 >> 3;
    const int rh4  = rk4 & 4;

    const int fr = lane & 15;
    const int q  = lane >> 4;
    const int wr = (wave >> 1) * 64;
    const int wc = (wave & 1) * 64;
    int aro[4], bro[4];
#pragma unroll
    for (int i = 0; i < 4; ++i) {
        const int r = wr + i * 16 + fr;
        aro[i] = r * 32 + ((q ^ ((r >> 1) & 3)) * 8);
    }
#pragma unroll
    for (int j = 0; j < 4; ++j) {
        const int r = wc + j * 16 + fr;
        bro[j] = r * 32 + ((q ^ ((r >> 1) & 3)) * 8);
    }

    f32x4 acc[4][4] = {};
    float4 rS[4];
    f16x8 aH[4], bH[4];
    const int NT = K >> 5;

    auto stageG = [&](f16_t* buf, int kt) {
#pragma unroll
        for (int c = 0; c < 2; ++c) {
            const long go = (long)(gbase + c * 64 + srow) * K + kt + sslot * 8;
            GLOAD_LDS16(GhB + go, &buf[gOff + c * 2048 + wdst]);
        }
    };
    auto loadR = [&](int kt) {
#pragma unroll
        for (int i = 0; i < 4; ++i)
            rS[i] = *(const float4*)&RfB[(long)(rbase + i * 32 + rrow) * K + kt + rk4];
    };
    auto writeR = [&](f16_t* buf) {
#pragma unroll
        for (int i = 0; i < 4; ++i) {
            const int row = i * 32 + rrow;
            const int eo  = row * 32 + ((rgr ^ ((row >> 1) & 3)) * 8) + rh4;
            f16x4 h4;
            h4[0] = (f16_t)rS[i].x; h4[1] = (f16_t)rS[i].y;
            h4[2] = (f16_t)rS[i].z; h4[3] = (f16_t)rS[i].w;
            *(f16x4*)&buf[rOff + eo] = h4;
        }
    };
    auto readF = [&](const f16_t* buf) {
#pragma unroll
        for (int i = 0; i < 4; ++i) aH[i] = *(const f16x8*)&buf[aro[i]];
#pragma unroll
        for (int j = 0; j < 4; ++j) bH[j] = *(const f16x8*)&buf[4096 + bro[j]];
    };

    loadR(0);
    stageG(lds[0], 0);
    writeR(lds[0]);
    loadR(32);
    asm volatile("s_waitcnt vmcnt(4)" ::: "memory");
    asm volatile("s_waitcnt lgkmcnt(0)" ::: "memory");
    __builtin_amdgcn_s_barrier();
    readF(lds[0]);
    asm volatile("s_waitcnt lgkmcnt(0)" ::: "memory");
    __builtin_amdgcn_s_barrier();

    for (int t = 0; t < NT; ++t) {
        f16_t* nxt = lds[(t & 1) ^ 1];
        const bool pf = (t + 1 < NT);

        if (pf) {
            writeR(nxt);
            stageG(nxt, (t + 1) << 5);
            if (t + 2 < NT) loadR((t + 2) << 5);
        }
#pragma unroll
        for (int j = 0; j < 4; ++j)
#pragma unroll
            for (int i = 0; i < 4; ++i)
                acc[i][j] = MFMA16H(aH[i], bH[j], acc[i][j]);

        if (pf && (t + 2 < NT))
            asm volatile("s_waitcnt vmcnt(4)" ::: "memory");
        else
            asm volatile("s_waitcnt vmcnt(0)" ::: "memory");
        asm volatile("s_waitcnt lgkmcnt(0)" ::: "memory");
        __builtin_amdgcn_s_barrier();
        if (pf) {
            readF(nxt);
            asm volatile("s_waitcnt lgkmcnt(0)" ::: "memory");
        }
        __builtin_amdgcn_s_barrier();
    }

    const int frow = q * 4;
#pragma unroll
    for (int i = 0; i < 4; ++i) {
        const int rgl = row0 + wr + i * 16 + frow;
#pragma unroll
        for (int j = 0; j < 4; ++j) {
            const int cg = col0 + wc + j * 16 + fr;
            if constexpr (EPI == 2) {
                f16_t* C = (f16_t*)C0 + bz * sC;
#pragma unroll
                for (int r = 0; r < 4; ++r)
                    C[(long)(rgl + r) * N + cg] = (f16_t)acc[i][j][r];
            } else if constexpr (EPI == 0) {
                float* C = (float*)C0 + bz * sC;
#pragma unroll
                for (int r = 0; r < 4; ++r)
                    C[(long)(rgl + r) * N + cg] = acc[i][j][r];
            } else {
                float* C = (float*)C0 + bz * sC;
                const float badd = bias[cg];
#pragma unroll
                for (int r = 0; r < 4; ++r)
                    C[(long)(rgl + r) * N + cg] = acc[i][j][r] + badd;
            }
        }
    }
}

// ---------------------------------------------------------------------------
// Plain-f16 MFMA GEMM, both operands gload: C = A @ B'^T (+bias).
// EPI: 0 = f32, 2 = f16, 3 = f32+bias.
template<int EPI>
__global__ __launch_bounds__(256)
void gemm_h(const f16_t* __restrict__ A, const f16_t* __restrict__ B,
            const float* __restrict__ bias, void* __restrict__ C0,
            int M, int N, int K, long sA, long sB, long sC)
{
    __shared__ f16_t lds[2][8192];

    const int tid  = threadIdx.x;
    const int wave = tid >> 6;
    const int lane = tid & 63;

    const int gx = gridDim.x, gy = gridDim.y;
    const long nwg = (long)gx * gy * gridDim.z;
    const long fo  = ((long)blockIdx.z * gy + blockIdx.y) * gx + blockIdx.x;
    const long f2 = (fo & 7) * (nwg >> 3) + (fo >> 3);
    const int bx  = (int)(f2 % gx);
    const int by  = (int)((f2 / gx) % gy);
    const long bz = f2 / ((long)gx * gy);

    const f16_t* Ab = A + bz * sA;
    const f16_t* Bb = B + bz * sB;

    const int row0 = by * 128;
    const int col0 = bx * 128;

    const int srow  = wave * 16 + (lane >> 2);
    const int sslot = (lane & 3) ^ ((srow >> 1) & 3);
    const int wdst  = wave * 512;
    const long aOff0 = (long)(row0 + srow) * K + sslot * 8;
    const long aOff1 = (long)(row0 + 64 + srow) * K + sslot * 8;
    const long bOff0 = (long)(col0 + srow) * K + sslot * 8;
    const long bOff1 = (long)(col0 + 64 + srow) * K + sslot * 8;

    const int fr = lane & 15;
    const int q  = lane >> 4;
    const int wr = (wave >> 1) * 64;
    const int wc = (wave & 1) * 64;
    int aro[4], bro[4];
#pragma unroll
    for (int i = 0; i < 4; ++i) {
        const int r = wr + i * 16 + fr;
        aro[i] = r * 32 + ((q ^ ((r >> 1) & 3)) * 8);
    }
#pragma unroll
    for (int j = 0; j < 4; ++j) {
        const int r = wc + j * 16 + fr;
        bro[j] = r * 32 + ((q ^ ((r >> 1) & 3)) * 8);
    }

    f32x4 acc[4][4] = {};
    const int NT = K >> 5;

#define STAGE(buf, kt) do {                                   \
        GLOAD_LDS16(Ab + aOff0 + (kt), &(buf)[wdst]);         \
        GLOAD_LDS16(Ab + aOff1 + (kt), &(buf)[2048 + wdst]);  \
        GLOAD_LDS16(Bb + bOff0 + (kt), &(buf)[4096 + wdst]);  \
        GLOAD_LDS16(Bb + bOff1 + (kt), &(buf)[6144 + wdst]);  \
    } while (0)

    STAGE(lds[0], 0);

    for (int t = 0; t < NT; ++t) {
        const f16_t* cur = lds[t & 1];
        f16_t* nxt = lds[(t & 1) ^ 1];
        const bool pf = (t + 1 < NT);

        __builtin_amdgcn_sched_barrier(0);
        __builtin_amdgcn_s_barrier();
        if (pf) {
            STAGE(nxt, (t + 1) << 5);
            asm volatile("s_waitcnt vmcnt(4)" ::: "memory");
        } else {
            asm volatile("s_waitcnt vmcnt(0)" ::: "memory");
        }
        __builtin_amdgcn_s_barrier();
        __builtin_amdgcn_sched_barrier(0);

        f16x8 aH[4], bH[4];
#pragma unroll
        for (int i = 0; i < 4; ++i) aH[i] = *(const f16x8*)&cur[aro[i]];
#pragma unroll
        for (int j = 0; j < 4; ++j) bH[j] = *(const f16x8*)&cur[4096 + bro[j]];

#pragma unroll
        for (int j = 0; j < 4; ++j)
#pragma unroll
            for (int i = 0; i < 4; ++i)
                acc[i][j] = MFMA16H(aH[i], bH[j], acc[i][j]);
    }
#undef STAGE

    const int frow = q * 4;
#pragma unroll
    for (int i = 0; i < 4; ++i) {
        const int rgl = row0 + wr + i * 16 + frow;
#pragma unroll
        for (int j = 0; j < 4; ++j) {
            const int cg = col0 + wc + j * 16 + fr;
            if constexpr (EPI == 2) {
                f16_t* C = (f16_t*)C0 + bz * sC;
#pragma unroll
                for (int r = 0; r < 4; ++r)
                    C[(long)(rgl + r) * N + cg] = (f16_t)acc[i][j][r];
            } else if constexpr (EPI == 0) {
                float* C = (float*)C0 + bz * sC;
#pragma unroll
                for (int r = 0; r < 4; ++r)
                    C[(long)(rgl + r) * N + cg] = acc[i][j][r];
            } else {
                float* C = (float*)C0 + bz * sC;
                const float badd = bias[cg];
#pragma unroll
                for (int r = 0; r < 4; ++r)
                    C[(long)(rgl + r) * N + cg] = acc[i][j][r] + badd;
            }
        }
    }
}

// ---------------------------------------------------------------------------
// Row softmax over length-1024 rows, f32 in place + f16 copy.
__global__ __launch_bounds__(256)
void softmax_rows(float* __restrict__ S, f16_t* __restrict__ Sh)
{
    const long row = (long)blockIdx.x * 4 + (threadIdx.x >> 6);
    const int lane = threadIdx.x & 63;
    float* p = S + row * (long)TENC;

    float4 v[4];
    float m = -INFINITY;
#pragma unroll
    for (int i = 0; i < 4; ++i) {
        v[i] = *(const float4*)&p[i * 256 + lane * 4];
        m = fmaxf(fmaxf(fmaxf(v[i].x, v[i].y), fmaxf(v[i].z, v[i].w)), m);
    }
#pragma unroll
    for (int o = 32; o; o >>= 1) m = fmaxf(m, __shfl_xor(m, o, 64));

    float s = 0.f;
#pragma unroll
    for (int i = 0; i < 4; ++i) {
        v[i].x = __expf(v[i].x - m);
        v[i].y = __expf(v[i].y - m);
        v[i].z = __expf(v[i].z - m);
        v[i].w = __expf(v[i].w - m);
        s += v[i].x + v[i].y + v[i].z + v[i].w;
    }
#pragma unroll
    for (int o = 32; o; o >>= 1) s += __shfl_xor(s, o, 64);

    const float inv = 1.0f / s;
#pragma unroll
    for (int i = 0; i < 4; ++i) {
        v[i].x *= inv; v[i].y *= inv; v[i].z *= inv; v[i].w *= inv;
        *(float4*)&p[i * 256 + lane * 4] = v[i];
        if (Sh) {
            f16x4 h;
            h[0] = (f16_t)v[i].x; h[1] = (f16_t)v[i].y;
            h[2] = (f16_t)v[i].z; h[3] = (f16_t)v[i].w;
            *(f16x4*)&Sh[row * (long)TENC + i * 256 + lane * 4] = h;
        }
    }
}

// ---------------------------------------------------------------------------
// fp32 fallback GEMM (safety net for tiny ws)
#define TILE_M 64
#define TILE_N 64
#define TILE_K 16
template<bool B_TRANS, bool ADD_BIAS>
__global__ __launch_bounds__(256)
void gemm_f32(const float* __restrict__ A, const float* __restrict__ Bm,
              const float* __restrict__ bias, float* __restrict__ C,
              int M, int N, int K, int lda, int ldb,
              long strideA, long strideB, long strideC)
{
    __shared__ float As[TILE_K][TILE_M + 4];
    __shared__ float Bs[TILE_K][TILE_N + 4];
    const int b = blockIdx.z;
    A += (long)b * strideA; Bm += (long)b * strideB; C += (long)b * strideC;
    const int tid = threadIdx.x;
    const int tx = tid & 15, ty = tid >> 4;
    const int row0 = blockIdx.y * TILE_M, col0 = blockIdx.x * TILE_N;
    const int am = tid >> 2, ak = (tid & 3) * 4;
    float acc[4][4] = {};
    for (int kt = 0; kt < K; kt += TILE_K) {
        float4 a4 = *(const float4*)&A[(long)(row0 + am) * lda + kt + ak];
        float4 b4;
        if (B_TRANS) b4 = *(const float4*)&Bm[(long)(col0 + am) * ldb + kt + ak];
        else {
            const int bk_ = tid >> 4, bn = (tid & 15) * 4;
            b4 = *(const float4*)&Bm[(long)(kt + bk_) * ldb + col0 + bn];
        }
        __syncthreads();
        As[ak + 0][am] = a4.x; As[ak + 1][am] = a4.y;
        As[ak + 2][am] = a4.z; As[ak + 3][am] = a4.w;
        if (B_TRANS) {
            Bs[ak + 0][am] = b4.x; Bs[ak + 1][am] = b4.y;
            Bs[ak + 2][am] = b4.z; Bs[ak + 3][am] = b4.w;
        } else {
            const int bk_ = tid >> 4, bn = (tid & 15) * 4;
            *(float4*)&Bs[bk_][bn] = b4;
        }
        __syncthreads();
#pragma unroll
        for (int k = 0; k < TILE_K; ++k) {
            float4 av = *(const float4*)&As[k][ty * 4];
            float4 bv4 = *(const float4*)&Bs[k][tx * 4];
            float ar[4] = {av.x, av.y, av.z, av.w};
            float br[4] = {bv4.x, bv4.y, bv4.z, bv4.w};
#pragma unroll
            for (int i = 0; i < 4; ++i)
#pragma unroll
                for (int j = 0; j < 4; ++j)
                    acc[i][j] = fmaf(ar[i], br[j], acc[i][j]);
        }
    }
    float4 bias4 = make_float4(0.f, 0.f, 0.f, 0.f);
    if (ADD_BIAS) bias4 = *(const float4*)&bias[col0 + tx * 4];
#pragma unroll
    for (int i = 0; i < 4; ++i) {
        float4 o;
        o.x = acc[i][0] + bias4.x; o.y = acc[i][1] + bias4.y;
        o.z = acc[i][2] + bias4.z; o.w = acc[i][3] + bias4.w;
        *(float4*)&C[(long)(row0 + ty * 4 + i) * N + col0 + tx * 4] = o;
    }
}

// ---------------------------------------------------------------------------
extern "C" void kernel_launch(void* const* d_in, const int* in_sizes, int n_in,
                              void* d_out, int out_size, void* d_ws, size_t ws_size,
                              hipStream_t stream)
{
    const float* enc = (const float*)d_in[0];   // [32,1024,512]
    const float* dec = (const float*)d_in[1];   // [32,512,512]
    const float* Wk  = (const float*)d_in[2];   // [512,512]
    const float* Wv  = (const float*)d_in[4];   // [512,512]
    const float* bv  = (const float*)d_in[5];   // [512]

    const long nD = (long)BB * TDEC * NST;      // 8388608

    float* ctx   = (float*)d_out;               // [32,512,512]
    float* attnF = ctx + nD;                    // [32,512,1024]

    const size_t need = 68157440;
    const dim3 blk(256);

    if (ws_size < need) {
        float* ws = (float*)d_ws;
        gemm_f32<true, false><<<dim3(DDIM / 64, (BB * TDEC) / 64, 1), blk, 0, stream>>>(
            dec, Wk, nullptr, ws, BB * TDEC, DDIM, NST, NST, NST, 0, 0, 0);
        gemm_f32<true, false><<<dim3(TENC / 64, TDEC / 64, BB), blk, 0, stream>>>(
            ws, enc, nullptr, attnF, TDEC, TENC, DDIM, DDIM, DDIM,
            (long)TDEC * DDIM, (long)TENC * DDIM, (long)TDEC * TENC);
        softmax_rows<<<(BB * TDEC) / 4, blk, 0, stream>>>(attnF, nullptr);
        gemm_f32<false, false><<<dim3(DDIM / 64, TDEC / 64, BB), blk, 0, stream>>>(
            attnF, enc, nullptr, ws, TDEC, DDIM, TENC, TENC, DDIM,
            (long)TDEC * TENC, (long)TENC * DDIM, (long)TDEC * DDIM);
        gemm_f32<false, true><<<dim3(NST / 64, (BB * TDEC) / 64, 1), blk, 0, stream>>>(
            ws, Wv, bv, ctx, BB * TDEC, NST, DDIM, DDIM, NST, 0, 0, 0);
        return;
    }

    // ws: EVT 33.55MB | Ef16 33.55MB | Wk16 0.5MB | WvT16 0.5MB
    char* w = (char*)d_ws;
    f16_t* EVT   = (f16_t*)(w);
    f16_t* Ef16  = (f16_t*)(w + 33554432);
    f16_t* Wk16  = (f16_t*)(w + 67108864);
    f16_t* WvT16 = (f16_t*)(w + 67633152);
    f16_t* attnB = Ef16;   // alias: live only after score+EVT consumed Ef16

    // DK16 in the not-yet-written ctx output region (16.8MB; dead after score)
    f16_t* DK16 = (f16_t*)ctx;

    // 1) fused prep: enc->f16, Wk->f16, Wv->f16^T  (dec handled in DK staging)
    prep_convert<<<8384, blk, 0, stream>>>(enc, Wk, Wv, Ef16, Wk16, WvT16);

    // 2) DK[q,d] = sum_n dec[q,n] Wk[d,n]  (dec f32 reg-staged) -> f16
    gemm_rs<1, 2><<<dim3(DDIM / 128, (BB * TDEC) / 128, 1), blk, 0, stream>>>(
        dec, Wk16, nullptr, DK16,
        BB * TDEC, DDIM, NST, 0, 0, 0);

    // 3) score[q,te] = sum_d DK[q,d] enc16[te,d] -> f32 attn region
    gemm_h<0><<<dim3(TENC / 128, TDEC / 128, BB), blk, 0, stream>>>(
        DK16, Ef16, nullptr, attnF,
        TDEC, TENC, DDIM,
        (long)TDEC * DDIM, (long)TENC * DDIM, (long)TDEC * TENC);

    // 4) EVT[v,te] = sum_d Wv[d,v] enc16[te,d] -> f16
    gemm_h<2><<<dim3(TENC / 128, NST / 128, BB), blk, 0, stream>>>(
        WvT16, Ef16, nullptr, EVT,
        NST, TENC, DDIM,
        0, (long)TENC * DDIM, (long)NST * TENC);

    // 5) softmax f32 in place + f16 copy over the dead Ef16 region
    softmax_rows<<<(BB * TDEC) / 4, blk, 0, stream>>>(attnF, attnB);

    // 6) ctx = attn @ EV + bv  (attnB f16 gload, EVT gload) -> f32+bias
    gemm_h<3><<<dim3(NST / 128, TDEC / 128, BB), blk, 0, stream>>>(
        attnB, EVT, bv, ctx,
        TDEC, NST, TENC,
        (long)TDEC * TENC, (long)NST * TENC, (long)TDEC * NST);
}